// Round 1
// baseline (934.726 us; speedup 1.0000x reference)
//
#include <hip/hip_runtime.h>
#include <math.h>

#define NE 1600000
#define NN 100000

typedef __attribute__((ext_vector_type(8))) short bf16x8;
typedef __attribute__((ext_vector_type(4))) float f32x4;

static __device__ inline short f2bf(float f) {
  unsigned u = __float_as_uint(f);
  u += 0x7FFFu + ((u >> 16) & 1u);
  return (short)(u >> 16);
}

// ws layout (floats): sum[NN*32] | sumsq[NN*32] | mx[NN*32] | mn[NN*32] | cnt[NN]
__global__ void k_init(float* __restrict__ ws) {
  int i = blockIdx.x * 256 + threadIdx.x;
  const int T = NN * 32;
  if (i < T) {
    ws[i] = 0.f;
    ws[T + i] = 0.f;
    ws[2 * T + i] = -INFINITY;
    ws[3 * T + i] = INFINITY;
    if ((i & 31) == 0) ws[4 * T + (i >> 5)] = 0.f;
  }
}

__global__ void k_edge(const float* __restrict__ msg, const int* __restrict__ dst,
                       float* __restrict__ ws) {
  long long i = (long long)blockIdx.x * 256 + threadIdx.x;
  if (i >= (long long)NE * 32) return;
  int e = (int)(i >> 5), c = (int)(i & 31);
  int n = dst[e];
  float v = msg[i];
  if (__float_as_uint(v) == 0x80000000u) v = 0.f;  // canonicalize -0.0
  const int T = NN * 32;
  int a = n * 32 + c;
  atomicAdd(&ws[a], v);
  atomicAdd(&ws[T + a], v * v);
  if (v >= 0.f) {
    atomicMax((int*)&ws[2 * T + a], __float_as_int(v));
    atomicMin((int*)&ws[3 * T + a], __float_as_int(v));
  } else {
    atomicMin((unsigned int*)&ws[2 * T + a], __float_as_uint(v));
    atomicMax((unsigned int*)&ws[3 * T + a], __float_as_uint(v));
  }
  if (c == 0) atomicAdd(&ws[4 * T + n], 1.f);
}

// Node pass: one wave per 16 nodes. Lane l: node r=l&15, channel octet oct=l>>4.
// A-frag (16x16x32 bf16): A[row=l%16][k=(l/16)*8+i]. B staged in LDS in frag order.
// C/D: col=lane&15 (out channel within 16-tile), row=(lane>>4)*4+j (node within 16).
__global__ __launch_bounds__(256) void k_node(const float* __restrict__ ws,
                                              const float* __restrict__ W,
                                              const float* __restrict__ bias,
                                              float* __restrict__ out) {
  __shared__ short Bf[12 * 4 * 64 * 8];  // [kt][ct][lane][i], bf16 = 49152 B
  for (int j = threadIdx.x; j < 12 * 4 * 64 * 8; j += 256) {
    int i = j & 7, l = (j >> 3) & 63, ct = (j >> 9) & 3, kt = j >> 11;
    int col = ct * 16 + (l & 15);         // output channel
    int k = kt * 32 + (l >> 4) * 8 + i;   // k index into 384
    Bf[j] = f2bf(W[col * 384 + k]);
  }
  __syncthreads();

  const int T = NN * 32;
  int wid = threadIdx.x >> 6, lane = threadIdx.x & 63;
  int r = lane & 15, oct = lane >> 4;

  int nb = (blockIdx.x * 4 + wid) * 16;
  if (nb >= NN) return;  // NN % 16 == 0, so surviving waves are fully valid
  int node = nb + r;
  int sb = node * 32 + oct * 8;

  f32x4 sv0 = *(const f32x4*)(ws + sb);
  f32x4 sv1 = *(const f32x4*)(ws + sb + 4);
  f32x4 qv0 = *(const f32x4*)(ws + T + sb);
  f32x4 qv1 = *(const f32x4*)(ws + T + sb + 4);
  f32x4 xv0 = *(const f32x4*)(ws + 2 * T + sb);
  f32x4 xv1 = *(const f32x4*)(ws + 2 * T + sb + 4);
  f32x4 nv0 = *(const f32x4*)(ws + 3 * T + sb);
  f32x4 nv1 = *(const f32x4*)(ws + 3 * T + sb + 4);
  float dgr = ws[4 * T + node];

  float deg = fmaxf(dgr, 1.f);
  float inv = 1.f / deg;
  float amp = logf(deg + 1.f);
  float att = 1.f / (deg + 1.f);

  float mean[8], stdv[8], mxv[8], mnv[8];
#pragma unroll
  for (int i2 = 0; i2 < 8; i2++) {
    float s = (i2 < 4) ? sv0[i2 & 3] : sv1[i2 & 3];
    float q = (i2 < 4) ? qv0[i2 & 3] : qv1[i2 & 3];
    float x = (i2 < 4) ? xv0[i2 & 3] : xv1[i2 & 3];
    float m = (i2 < 4) ? nv0[i2 & 3] : nv1[i2 & 3];
    float me = s * inv;
    float va = fmaxf(q * inv - me * me, 0.f);
    mean[i2] = me;
    stdv[i2] = sqrtf(va + 1e-8f);
    mxv[i2] = (x == -INFINITY) ? 0.f : x;
    mnv[i2] = (m == INFINITY) ? 0.f : m;
  }

  f32x4 acc[4] = {{0.f, 0.f, 0.f, 0.f},
                  {0.f, 0.f, 0.f, 0.f},
                  {0.f, 0.f, 0.f, 0.f},
                  {0.f, 0.f, 0.f, 0.f}};
  float scal[3] = {1.f, amp, att};
  const bf16x8* Bp = (const bf16x8*)Bf;
#pragma unroll
  for (int kt = 0; kt < 12; kt++) {
    const float* ag = (kt < 3) ? mean : (kt < 6) ? mxv : (kt < 9) ? mnv : stdv;
    float sc = scal[kt % 3];
    bf16x8 af;
#pragma unroll
    for (int i2 = 0; i2 < 8; i2++) af[i2] = f2bf(ag[i2] * sc);
#pragma unroll
    for (int ct = 0; ct < 4; ct++) {
      acc[ct] = __builtin_amdgcn_mfma_f32_16x16x32_bf16(af, Bp[(kt * 4 + ct) * 64 + lane],
                                                        acc[ct], 0, 0, 0);
    }
  }

#pragma unroll
  for (int ct = 0; ct < 4; ct++) {
    int ocol = ct * 16 + r;
    float bb = bias[ocol];
#pragma unroll
    for (int j = 0; j < 4; j++) {
      int orow = nb + oct * 4 + j;
      out[orow * 64 + ocol] = acc[ct][j] + bb;
    }
  }
}

extern "C" void kernel_launch(void* const* d_in, const int* in_sizes, int n_in,
                              void* d_out, int out_size, void* d_ws, size_t ws_size,
                              hipStream_t stream) {
  const float* msg = (const float*)d_in[0];
  const int* dst = (const int*)d_in[1];
  const float* W = (const float*)d_in[3];
  const float* bias = (const float*)d_in[4];
  float* ws = (float*)d_ws;
  float* out = (float*)d_out;

  k_init<<<(NN * 32 + 255) / 256, 256, 0, stream>>>(ws);
  k_edge<<<(NE * 32 + 255) / 256, 256, 0, stream>>>(msg, dst, ws);
  k_node<<<(NN + 63) / 64, 256, 0, stream>>>(ws, W, bias, out);
}

// Round 2
// 303.984 us; speedup vs baseline: 3.0749x; 3.0749x over previous
//
#include <hip/hip_runtime.h>
#include <math.h>

#define NE 1600000
#define NN 100000
#define NBLK ((NN + 255) / 256)  // 391

typedef __attribute__((ext_vector_type(8))) short bf16x8;
typedef __attribute__((ext_vector_type(4))) float f32x4;

static __device__ inline short f2bf(float f) {
  unsigned u = __float_as_uint(f);
  u += 0x7FFFu + ((u >> 16) & 1u);
  return (short)(u >> 16);
}

__global__ void k_zero(int* __restrict__ cnt) {
  int i = blockIdx.x * 256 + threadIdx.x;
  if (i < NN) cnt[i] = 0;
}

__global__ void k_count(const int* __restrict__ dst, int* __restrict__ cnt) {
  int e = blockIdx.x * 256 + threadIdx.x;
  if (e < NE) atomicAdd(&cnt[dst[e]], 1);
}

__global__ void k_scan1(const int* __restrict__ cnt, int* __restrict__ bsum) {
  __shared__ int s[256];
  int t = threadIdx.x, i = blockIdx.x * 256 + t;
  s[t] = (i < NN) ? cnt[i] : 0;
  __syncthreads();
  for (int d = 128; d > 0; d >>= 1) {
    if (t < d) s[t] += s[t + d];
    __syncthreads();
  }
  if (t == 0) bsum[blockIdx.x] = s[0];
}

__global__ void k_scan2(int* __restrict__ bsum, int* __restrict__ off) {
  __shared__ int s[512];
  int t = threadIdx.x;
  int v = (t < NBLK) ? bsum[t] : 0;
  s[t] = v;
  __syncthreads();
  for (int d = 1; d < 512; d <<= 1) {
    int x = (t >= d) ? s[t - d] : 0;
    __syncthreads();
    s[t] += x;
    __syncthreads();
  }
  if (t < NBLK) bsum[t] = s[t] - v;  // exclusive prefix of block sums
  if (t == 0) off[NN] = NE;
}

__global__ void k_scan3(const int* __restrict__ cnt, const int* __restrict__ bsum,
                        int* __restrict__ off, int* __restrict__ cur) {
  __shared__ int s[256];
  int t = threadIdx.x, i = blockIdx.x * 256 + t;
  int v = (i < NN) ? cnt[i] : 0;
  s[t] = v;
  __syncthreads();
  for (int d = 1; d < 256; d <<= 1) {
    int x = (t >= d) ? s[t - d] : 0;
    __syncthreads();
    s[t] += x;
    __syncthreads();
  }
  int ex = s[t] - v + bsum[blockIdx.x];
  if (i < NN) {
    off[i] = ex;
    cur[i] = ex;
  }
}

__global__ void k_scatter(const int* __restrict__ dst, int* __restrict__ cur,
                          int* __restrict__ eid) {
  int e = blockIdx.x * 256 + threadIdx.x;
  if (e < NE) {
    int n = dst[e];
    int p = atomicAdd(&cur[n], 1);
    eid[p] = e;
  }
}

// Fused gather + stats + MFMA projection.
// Wave = 16 nodes. Lane l: node r=l&15, channel octet oct=l>>4 (8 ch each).
// A-frag (16x16x32 bf16): A[row=l%16][k=(l/16)*8+i]. B staged in LDS in frag order.
// C/D: col=lane&15 (out channel in 16-tile), row=(lane>>4)*4+j (node in 16-tile).
__global__ __launch_bounds__(256) void k_fused(const float* __restrict__ msg,
                                               const int* __restrict__ off,
                                               const int* __restrict__ eid,
                                               const float* __restrict__ W,
                                               const float* __restrict__ bias,
                                               float* __restrict__ out) {
  __shared__ short Bf[12 * 4 * 64 * 8];  // [kt][ct][lane][i] bf16, 49152 B
  for (int j = threadIdx.x; j < 12 * 4 * 64 * 8; j += 256) {
    int i = j & 7, l = (j >> 3) & 63, ct = (j >> 9) & 3, kt = j >> 11;
    int col = ct * 16 + (l & 15);        // output channel
    int k = kt * 32 + (l >> 4) * 8 + i;  // k index into 384
    Bf[j] = f2bf(W[col * 384 + k]);
  }
  __syncthreads();

  int wid = threadIdx.x >> 6, lane = threadIdx.x & 63;
  int r = lane & 15, oct = lane >> 4;
  int nb = (blockIdx.x * 4 + wid) * 16;
  if (nb >= NN) return;  // NN % 16 == 0: surviving waves fully valid
  int node = nb + r;

  int e0 = off[node], e1 = off[node + 1];

  float sv[8], qv[8], xv[8], nv[8];
#pragma unroll
  for (int i = 0; i < 8; i++) {
    sv[i] = 0.f;
    qv[i] = 0.f;
    xv[i] = -INFINITY;
    nv[i] = INFINITY;
  }

  for (int p = e0; p < e1; ++p) {
    int e = eid[p];
    const f32x4* rp = (const f32x4*)(msg + (size_t)e * 32 + oct * 8);
    f32x4 a = rp[0], b = rp[1];
#pragma unroll
    for (int i = 0; i < 4; i++) {
      float v0 = a[i], v1 = b[i];
      sv[i] += v0;
      qv[i] += v0 * v0;
      xv[i] = fmaxf(xv[i], v0);
      nv[i] = fminf(nv[i], v0);
      sv[i + 4] += v1;
      qv[i + 4] += v1 * v1;
      xv[i + 4] = fmaxf(xv[i + 4], v1);
      nv[i + 4] = fminf(nv[i + 4], v1);
    }
  }

  float degr = (float)(e1 - e0);
  float deg = fmaxf(degr, 1.f);
  float inv = 1.f / deg;
  float amp = logf(deg + 1.f);
  float att = 1.f / (deg + 1.f);

#pragma unroll
  for (int i = 0; i < 8; i++) {
    float me = sv[i] * inv;
    float va = fmaxf(qv[i] * inv - me * me, 0.f);
    sv[i] = me;                  // mean
    qv[i] = sqrtf(va + 1e-8f);   // std
    xv[i] = (xv[i] == -INFINITY) ? 0.f : xv[i];
    nv[i] = (nv[i] == INFINITY) ? 0.f : nv[i];
  }

  f32x4 acc[4] = {{0.f, 0.f, 0.f, 0.f},
                  {0.f, 0.f, 0.f, 0.f},
                  {0.f, 0.f, 0.f, 0.f},
                  {0.f, 0.f, 0.f, 0.f}};
  float scal[3] = {1.f, amp, att};
  const bf16x8* Bp = (const bf16x8*)Bf;
#pragma unroll
  for (int kt = 0; kt < 12; kt++) {
    const float* ag = (kt < 3) ? sv : (kt < 6) ? xv : (kt < 9) ? nv : qv;
    float sc = scal[kt % 3];
    bf16x8 af;
#pragma unroll
    for (int i = 0; i < 8; i++) af[i] = f2bf(ag[i] * sc);
#pragma unroll
    for (int ct = 0; ct < 4; ct++) {
      acc[ct] = __builtin_amdgcn_mfma_f32_16x16x32_bf16(af, Bp[(kt * 4 + ct) * 64 + lane],
                                                        acc[ct], 0, 0, 0);
    }
  }

#pragma unroll
  for (int ct = 0; ct < 4; ct++) {
    int ocol = ct * 16 + r;
    float bb = bias[ocol];
#pragma unroll
    for (int j = 0; j < 4; j++) {
      int orow = nb + oct * 4 + j;
      out[orow * 64 + ocol] = acc[ct][j] + bb;
    }
  }
}

extern "C" void kernel_launch(void* const* d_in, const int* in_sizes, int n_in,
                              void* d_out, int out_size, void* d_ws, size_t ws_size,
                              hipStream_t stream) {
  const float* msg = (const float*)d_in[0];
  const int* dst = (const int*)d_in[1];
  const float* W = (const float*)d_in[3];
  const float* bias = (const float*)d_in[4];
  float* out = (float*)d_out;

  int* wsi = (int*)d_ws;
  int* cnt = wsi;                    // NN
  int* off = wsi + NN;               // NN+1
  int* cur = wsi + 2 * NN + 1;       // NN
  int* eid = wsi + 3 * NN + 1;       // NE
  int* bsum = wsi + 3 * NN + 1 + NE; // NBLK

  k_zero<<<NBLK, 256, 0, stream>>>(cnt);
  k_count<<<(NE + 255) / 256, 256, 0, stream>>>(dst, cnt);
  k_scan1<<<NBLK, 256, 0, stream>>>(cnt, bsum);
  k_scan2<<<1, 512, 0, stream>>>(bsum, off);
  k_scan3<<<NBLK, 256, 0, stream>>>(cnt, bsum, off, cur);
  k_scatter<<<(NE + 255) / 256, 256, 0, stream>>>(dst, cur, eid);
  k_fused<<<(NN / 16 + 3) / 4, 256, 0, stream>>>(msg, off, eid, W, bias, out);
}

// Round 3
// 272.513 us; speedup vs baseline: 3.4300x; 1.1155x over previous
//
#include <hip/hip_runtime.h>
#include <math.h>

#define NE 1600000
#define NN 100000
#define NBLK ((NN + 255) / 256)  // 391

typedef __attribute__((ext_vector_type(8))) short bf16x8;
typedef __attribute__((ext_vector_type(4))) float f32x4;

static __device__ inline short f2bf(float f) {
  unsigned u = __float_as_uint(f);
  u += 0x7FFFu + ((u >> 16) & 1u);
  return (short)(u >> 16);
}

__global__ void k_zero(int* __restrict__ cnt) {
  int i = blockIdx.x * 256 + threadIdx.x;
  if (i < NN) cnt[i] = 0;
}

__global__ void k_count(const int* __restrict__ dst, int* __restrict__ cnt) {
  int e = (blockIdx.x * 256 + threadIdx.x) * 4;
  if (e + 4 <= NE) {
    int4 d4 = *(const int4*)(dst + e);
    atomicAdd(&cnt[d4.x], 1);
    atomicAdd(&cnt[d4.y], 1);
    atomicAdd(&cnt[d4.z], 1);
    atomicAdd(&cnt[d4.w], 1);
  } else {
    for (; e < NE; ++e) atomicAdd(&cnt[dst[e]], 1);
  }
}

__global__ void k_scan1(const int* __restrict__ cnt, int* __restrict__ bsum) {
  __shared__ int s[256];
  int t = threadIdx.x, i = blockIdx.x * 256 + t;
  s[t] = (i < NN) ? cnt[i] : 0;
  __syncthreads();
  for (int d = 128; d > 0; d >>= 1) {
    if (t < d) s[t] += s[t + d];
    __syncthreads();
  }
  if (t == 0) bsum[blockIdx.x] = s[0];
}

// Per-block: reduce bsum[0..blockIdx) for the global base, then local scan.
__global__ void k_scan3(const int* __restrict__ cnt, const int* __restrict__ bsum,
                        int* __restrict__ off, int* __restrict__ cur) {
  __shared__ int pre[256];
  __shared__ int s[256];
  int t = threadIdx.x, b = blockIdx.x, i = b * 256 + t;
  int a = 0;
  for (int j = t; j < b; j += 256) a += bsum[j];
  pre[t] = a;
  __syncthreads();
  for (int d = 128; d > 0; d >>= 1) {
    if (t < d) pre[t] += pre[t + d];
    __syncthreads();
  }
  int base = pre[0];
  int v = (i < NN) ? cnt[i] : 0;
  s[t] = v;
  __syncthreads();
  for (int d = 1; d < 256; d <<= 1) {
    int x = (t >= d) ? s[t - d] : 0;
    __syncthreads();
    s[t] += x;
    __syncthreads();
  }
  int ex = s[t] - v + base;
  if (i < NN) {
    off[i] = ex;
    cur[i] = ex;
  }
  if (i == NN - 1) off[NN] = ex + v;  // == NE
}

__global__ void k_scatter(const int* __restrict__ dst, int* __restrict__ cur,
                          int* __restrict__ eid) {
  int e = (blockIdx.x * 256 + threadIdx.x) * 4;
  if (e + 4 <= NE) {
    int4 d4 = *(const int4*)(dst + e);
    int p0 = atomicAdd(&cur[d4.x], 1);
    eid[p0] = e;
    int p1 = atomicAdd(&cur[d4.y], 1);
    eid[p1] = e + 1;
    int p2 = atomicAdd(&cur[d4.z], 1);
    eid[p2] = e + 2;
    int p3 = atomicAdd(&cur[d4.w], 1);
    eid[p3] = e + 3;
  } else {
    for (; e < NE; ++e) {
      int p = atomicAdd(&cur[dst[e]], 1);
      eid[p] = e;
    }
  }
}

// Fused gather + stats + MFMA projection.
// 512 threads = 8 waves share one 48KB Bf (3 blocks/CU -> 24 waves/CU).
// Wave = 16 nodes. Lane l: node r=l&15, channel octet oct=l>>4 (8 ch each).
// Lanes r, r+16, r+32, r+48 walk the SAME node -> their 4x32B msg reads
// coalesce into one 128B row fetch per edge.
// A-frag (16x16x32 bf16): A[row=l%16][k=(l/16)*8+i]. B staged in LDS frag-order.
// C/D: col=lane&15 (out channel in 16-tile), row=(lane>>4)*4+j (node in 16-tile).
__global__ __launch_bounds__(512) void k_fused(const float* __restrict__ msg,
                                               const int* __restrict__ off,
                                               const int* __restrict__ eid,
                                               const float* __restrict__ W,
                                               const float* __restrict__ bias,
                                               float* __restrict__ out) {
  __shared__ short Bf[12 * 4 * 64 * 8];  // [kt][ct][lane][i] bf16, 49152 B
  for (int j = threadIdx.x; j < 12 * 4 * 64 * 8; j += 512) {
    int i = j & 7, l = (j >> 3) & 63, ct = (j >> 9) & 3, kt = j >> 11;
    int col = ct * 16 + (l & 15);        // output channel
    int k = kt * 32 + (l >> 4) * 8 + i;  // k index into 384
    Bf[j] = f2bf(W[col * 384 + k]);
  }
  __syncthreads();

  int wid = threadIdx.x >> 6, lane = threadIdx.x & 63;
  int r = lane & 15, oct = lane >> 4;
  int nb = (blockIdx.x * 8 + wid) * 16;
  if (nb >= NN) return;  // NN % 16 == 0: surviving waves fully valid
  int node = nb + r;

  int e0 = off[node], e1 = off[node + 1];

  float sv[8], qv[8], xv[8], nv[8];
#pragma unroll
  for (int i = 0; i < 8; i++) {
    sv[i] = 0.f;
    qv[i] = 0.f;
    xv[i] = -INFINITY;
    nv[i] = INFINITY;
  }

  // Unroll x4: 4 eid loads then 8 independent dwordx4 gathers in flight.
  int p = e0;
  int nfull = (e1 - e0) >> 2;
  for (int it = 0; it < nfull; ++it, p += 4) {
    int ea0 = eid[p], ea1 = eid[p + 1], ea2 = eid[p + 2], ea3 = eid[p + 3];
    const f32x4* r0 = (const f32x4*)(msg + (size_t)ea0 * 32 + oct * 8);
    const f32x4* r1 = (const f32x4*)(msg + (size_t)ea1 * 32 + oct * 8);
    const f32x4* r2 = (const f32x4*)(msg + (size_t)ea2 * 32 + oct * 8);
    const f32x4* r3 = (const f32x4*)(msg + (size_t)ea3 * 32 + oct * 8);
    f32x4 va0 = r0[0], vb0 = r0[1];
    f32x4 va1 = r1[0], vb1 = r1[1];
    f32x4 va2 = r2[0], vb2 = r2[1];
    f32x4 va3 = r3[0], vb3 = r3[1];
#pragma unroll
    for (int i = 0; i < 4; i++) {
      float w0 = va0[i], w1 = va1[i], w2 = va2[i], w3 = va3[i];
      sv[i] += w0 + w1 + w2 + w3;
      qv[i] += w0 * w0 + w1 * w1 + w2 * w2 + w3 * w3;
      xv[i] = fmaxf(fmaxf(xv[i], fmaxf(w0, w1)), fmaxf(w2, w3));
      nv[i] = fminf(fminf(nv[i], fminf(w0, w1)), fminf(w2, w3));
      float z0 = vb0[i], z1 = vb1[i], z2 = vb2[i], z3 = vb3[i];
      sv[i + 4] += z0 + z1 + z2 + z3;
      qv[i + 4] += z0 * z0 + z1 * z1 + z2 * z2 + z3 * z3;
      xv[i + 4] = fmaxf(fmaxf(xv[i + 4], fmaxf(z0, z1)), fmaxf(z2, z3));
      nv[i + 4] = fminf(fminf(nv[i + 4], fminf(z0, z1)), fminf(z2, z3));
    }
  }
  for (; p < e1; ++p) {
    int e = eid[p];
    const f32x4* rp = (const f32x4*)(msg + (size_t)e * 32 + oct * 8);
    f32x4 a = rp[0], b = rp[1];
#pragma unroll
    for (int i = 0; i < 4; i++) {
      float v0 = a[i], v1 = b[i];
      sv[i] += v0;
      qv[i] += v0 * v0;
      xv[i] = fmaxf(xv[i], v0);
      nv[i] = fminf(nv[i], v0);
      sv[i + 4] += v1;
      qv[i + 4] += v1 * v1;
      xv[i + 4] = fmaxf(xv[i + 4], v1);
      nv[i + 4] = fminf(nv[i + 4], v1);
    }
  }

  float degr = (float)(e1 - e0);
  float deg = fmaxf(degr, 1.f);
  float inv = 1.f / deg;
  float amp = logf(deg + 1.f);
  float att = 1.f / (deg + 1.f);

#pragma unroll
  for (int i = 0; i < 8; i++) {
    float me = sv[i] * inv;
    float va = fmaxf(qv[i] * inv - me * me, 0.f);
    sv[i] = me;                 // mean
    qv[i] = sqrtf(va + 1e-8f);  // std
    xv[i] = (xv[i] == -INFINITY) ? 0.f : xv[i];
    nv[i] = (nv[i] == INFINITY) ? 0.f : nv[i];
  }

  f32x4 acc[4] = {{0.f, 0.f, 0.f, 0.f},
                  {0.f, 0.f, 0.f, 0.f},
                  {0.f, 0.f, 0.f, 0.f},
                  {0.f, 0.f, 0.f, 0.f}};
  float scal[3] = {1.f, amp, att};
  const bf16x8* Bp = (const bf16x8*)Bf;
#pragma unroll
  for (int kt = 0; kt < 12; kt++) {
    const float* ag = (kt < 3) ? sv : (kt < 6) ? xv : (kt < 9) ? nv : qv;
    float sc = scal[kt % 3];
    bf16x8 af;
#pragma unroll
    for (int i = 0; i < 8; i++) af[i] = f2bf(ag[i] * sc);
#pragma unroll
    for (int ct = 0; ct < 4; ct++) {
      acc[ct] = __builtin_amdgcn_mfma_f32_16x16x32_bf16(af, Bp[(kt * 4 + ct) * 64 + lane],
                                                        acc[ct], 0, 0, 0);
    }
  }

#pragma unroll
  for (int ct = 0; ct < 4; ct++) {
    int ocol = ct * 16 + r;
    float bb = bias[ocol];
#pragma unroll
    for (int j = 0; j < 4; j++) {
      int orow = nb + oct * 4 + j;
      out[orow * 64 + ocol] = acc[ct][j] + bb;
    }
  }
}

extern "C" void kernel_launch(void* const* d_in, const int* in_sizes, int n_in,
                              void* d_out, int out_size, void* d_ws, size_t ws_size,
                              hipStream_t stream) {
  const float* msg = (const float*)d_in[0];
  const int* dst = (const int*)d_in[1];
  const float* W = (const float*)d_in[3];
  const float* bias = (const float*)d_in[4];
  float* out = (float*)d_out;

  int* wsi = (int*)d_ws;
  int* cnt = wsi;                     // NN
  int* off = wsi + NN;                // NN+1
  int* cur = wsi + 2 * NN + 1;        // NN
  int* eid = wsi + 3 * NN + 1;        // NE
  int* bsum = wsi + 3 * NN + 1 + NE;  // NBLK

  k_zero<<<NBLK, 256, 0, stream>>>(cnt);
  k_count<<<(NE / 4 + 255) / 256, 256, 0, stream>>>(dst, cnt);
  k_scan1<<<NBLK, 256, 0, stream>>>(cnt, bsum);
  k_scan3<<<NBLK, 256, 0, stream>>>(cnt, bsum, off, cur);
  k_scatter<<<(NE / 4 + 255) / 256, 256, 0, stream>>>(dst, cur, eid);
  k_fused<<<(NN / 16 + 7) / 8, 512, 0, stream>>>(msg, off, eid, W, bias, out);
}

// Round 4
// 128.119 us; speedup vs baseline: 7.2957x; 2.1270x over previous
//
#include <hip/hip_runtime.h>
#include <math.h>

#define NE 1600000
#define NN 100000
#define NBKT 391        // ceil(NN/256) buckets of 256 nodes
#define BINCH 8192      // edges per binning block
#define NBINBLK ((NE + BINCH - 1) / BINCH)  // 196

typedef __attribute__((ext_vector_type(8))) short bf16x8;
typedef __attribute__((ext_vector_type(4))) float f32x4;

static __device__ inline short f2bf(float f) {
  unsigned u = __float_as_uint(f);
  u += 0x7FFFu + ((u >> 16) & 1u);
  return (short)(u >> 16);
}

__global__ void k_init0(int* __restrict__ bktcnt) {
  int t = threadIdx.x;
  if (t < NBKT) bktcnt[t] = 0;
}

// Coarse histogram: LDS per-block, one global atomic per (block,bucket).
__global__ __launch_bounds__(256) void k_bktcount(const int* __restrict__ dst,
                                                  int* __restrict__ bktcnt) {
  __shared__ int hist[NBKT];
  int t = threadIdx.x;
  for (int j = t; j < NBKT; j += 256) hist[j] = 0;
  __syncthreads();
  int start = blockIdx.x * BINCH;
  int lim = min(BINCH, NE - start);
  for (int j = t; j < lim; j += 256) atomicAdd(&hist[dst[start + j] >> 8], 1);
  __syncthreads();
  for (int j = t; j < NBKT; j += 256) {
    int h = hist[j];
    if (h) atomicAdd(&bktcnt[j], h);
  }
}

// Scan 391 bucket counts -> bases; init cursors; fix up off[NN].
__global__ void k_bktscan(const int* __restrict__ bktcnt, int* __restrict__ bktoff,
                          int* __restrict__ bkcur, int* __restrict__ off) {
  __shared__ int s[512];
  int t = threadIdx.x;
  int v = (t < NBKT) ? bktcnt[t] : 0;
  s[t] = v;
  __syncthreads();
  for (int d = 1; d < 512; d <<= 1) {
    int x = (t >= d) ? s[t - d] : 0;
    __syncthreads();
    s[t] += x;
    __syncthreads();
  }
  if (t < NBKT) {
    int ex = s[t] - v;
    bktoff[t] = ex;
    bkcur[t] = ex;
  }
  if (t == 0) {
    bktoff[NBKT] = NE;
    off[NN] = NE;
  }
}

// Bin edges into bucket regions as (dst,e) pairs. All fine-grained atomics in
// LDS; global writes are contiguous ~21-pair runs per (block,bucket).
__global__ __launch_bounds__(256) void k_bin(const int* __restrict__ dst,
                                             int* __restrict__ bkcur,
                                             int2* __restrict__ pairs) {
  __shared__ int sdst[BINCH];
  __shared__ int hist[NBKT];
  int t = threadIdx.x;
  int start = blockIdx.x * BINCH;
  int lim = min(BINCH, NE - start);
  for (int j = t; j < NBKT; j += 256) hist[j] = 0;
  __syncthreads();
  for (int j = t; j < lim; j += 256) {
    int d = dst[start + j];
    sdst[j] = d;
    atomicAdd(&hist[d >> 8], 1);
  }
  __syncthreads();
  for (int j = t; j < NBKT; j += 256) {
    int h = hist[j];
    hist[j] = h ? atomicAdd(&bkcur[j], h) : 0;  // hist becomes local cursor base
  }
  __syncthreads();
  for (int j = t; j < lim; j += 256) {
    int d = sdst[j];
    int q = atomicAdd(&hist[d >> 8], 1);
    pairs[q] = make_int2(d, start + j);
  }
}

// One block per bucket: per-node count+scan in LDS (no global atomics), write
// off[] contiguously, scatter eid within the bucket's ~16KB L2-resident window.
__global__ __launch_bounds__(256) void k_build(const int2* __restrict__ pairs,
                                               const int* __restrict__ bktoff,
                                               int* __restrict__ off,
                                               int* __restrict__ eid) {
  __shared__ int cnt[256];
  __shared__ int loc[256];
  int b = blockIdx.x, t = threadIdx.x;
  int base = bktoff[b];
  int m = bktoff[b + 1] - base;
  cnt[t] = 0;
  __syncthreads();
  for (int i = t; i < m; i += 256) atomicAdd(&cnt[pairs[base + i].x & 255], 1);
  __syncthreads();
  int v = cnt[t];
  loc[t] = v;
  __syncthreads();
  for (int d = 1; d < 256; d <<= 1) {
    int x = (t >= d) ? loc[t - d] : 0;
    __syncthreads();
    loc[t] += x;
    __syncthreads();
  }
  int ex = base + loc[t] - v;  // global exclusive offset of node b*256+t
  int node = b * 256 + t;
  if (node < NN) off[node] = ex;
  __syncthreads();
  loc[t] = ex;  // cursors
  __syncthreads();
  for (int i = t; i < m; i += 256) {
    int2 pe = pairs[base + i];
    int p = atomicAdd(&loc[pe.x & 255], 1);
    eid[p] = pe.y;
  }
}

// Fused gather + stats + MFMA projection (unchanged from round 3).
// 512 threads = 8 waves share one 48KB Bf. Wave = 16 nodes.
// Lane l: node r=l&15, channel octet oct=l>>4; lanes r,r+16,r+32,r+48 walk the
// same node -> 4x32B reads coalesce to one 128B row per edge.
__global__ __launch_bounds__(512) void k_fused(const float* __restrict__ msg,
                                               const int* __restrict__ off,
                                               const int* __restrict__ eid,
                                               const float* __restrict__ W,
                                               const float* __restrict__ bias,
                                               float* __restrict__ out) {
  __shared__ short Bf[12 * 4 * 64 * 8];  // [kt][ct][lane][i] bf16, 49152 B
  for (int j = threadIdx.x; j < 12 * 4 * 64 * 8; j += 512) {
    int i = j & 7, l = (j >> 3) & 63, ct = (j >> 9) & 3, kt = j >> 11;
    int col = ct * 16 + (l & 15);
    int k = kt * 32 + (l >> 4) * 8 + i;
    Bf[j] = f2bf(W[col * 384 + k]);
  }
  __syncthreads();

  int wid = threadIdx.x >> 6, lane = threadIdx.x & 63;
  int r = lane & 15, oct = lane >> 4;
  int nb = (blockIdx.x * 8 + wid) * 16;
  if (nb >= NN) return;
  int node = nb + r;

  int e0 = off[node], e1 = off[node + 1];

  float sv[8], qv[8], xv[8], nv[8];
#pragma unroll
  for (int i = 0; i < 8; i++) {
    sv[i] = 0.f;
    qv[i] = 0.f;
    xv[i] = -INFINITY;
    nv[i] = INFINITY;
  }

  int p = e0;
  int nfull = (e1 - e0) >> 2;
  for (int it = 0; it < nfull; ++it, p += 4) {
    int ea0 = eid[p], ea1 = eid[p + 1], ea2 = eid[p + 2], ea3 = eid[p + 3];
    const f32x4* r0 = (const f32x4*)(msg + (size_t)ea0 * 32 + oct * 8);
    const f32x4* r1 = (const f32x4*)(msg + (size_t)ea1 * 32 + oct * 8);
    const f32x4* r2 = (const f32x4*)(msg + (size_t)ea2 * 32 + oct * 8);
    const f32x4* r3 = (const f32x4*)(msg + (size_t)ea3 * 32 + oct * 8);
    f32x4 va0 = r0[0], vb0 = r0[1];
    f32x4 va1 = r1[0], vb1 = r1[1];
    f32x4 va2 = r2[0], vb2 = r2[1];
    f32x4 va3 = r3[0], vb3 = r3[1];
#pragma unroll
    for (int i = 0; i < 4; i++) {
      float w0 = va0[i], w1 = va1[i], w2 = va2[i], w3 = va3[i];
      sv[i] += w0 + w1 + w2 + w3;
      qv[i] += w0 * w0 + w1 * w1 + w2 * w2 + w3 * w3;
      xv[i] = fmaxf(fmaxf(xv[i], fmaxf(w0, w1)), fmaxf(w2, w3));
      nv[i] = fminf(fminf(nv[i], fminf(w0, w1)), fminf(w2, w3));
      float z0 = vb0[i], z1 = vb1[i], z2 = vb2[i], z3 = vb3[i];
      sv[i + 4] += z0 + z1 + z2 + z3;
      qv[i + 4] += z0 * z0 + z1 * z1 + z2 * z2 + z3 * z3;
      xv[i + 4] = fmaxf(fmaxf(xv[i + 4], fmaxf(z0, z1)), fmaxf(z2, z3));
      nv[i + 4] = fminf(fminf(nv[i + 4], fminf(z0, z1)), fminf(z2, z3));
    }
  }
  for (; p < e1; ++p) {
    int e = eid[p];
    const f32x4* rp = (const f32x4*)(msg + (size_t)e * 32 + oct * 8);
    f32x4 a = rp[0], b = rp[1];
#pragma unroll
    for (int i = 0; i < 4; i++) {
      float v0 = a[i], v1 = b[i];
      sv[i] += v0;
      qv[i] += v0 * v0;
      xv[i] = fmaxf(xv[i], v0);
      nv[i] = fminf(nv[i], v0);
      sv[i + 4] += v1;
      qv[i + 4] += v1 * v1;
      xv[i + 4] = fmaxf(xv[i + 4], v1);
      nv[i + 4] = fminf(nv[i + 4], v1);
    }
  }

  float degr = (float)(e1 - e0);
  float deg = fmaxf(degr, 1.f);
  float inv = 1.f / deg;
  float amp = logf(deg + 1.f);
  float att = 1.f / (deg + 1.f);

#pragma unroll
  for (int i = 0; i < 8; i++) {
    float me = sv[i] * inv;
    float va = fmaxf(qv[i] * inv - me * me, 0.f);
    sv[i] = me;
    qv[i] = sqrtf(va + 1e-8f);
    xv[i] = (xv[i] == -INFINITY) ? 0.f : xv[i];
    nv[i] = (nv[i] == INFINITY) ? 0.f : nv[i];
  }

  f32x4 acc[4] = {{0.f, 0.f, 0.f, 0.f},
                  {0.f, 0.f, 0.f, 0.f},
                  {0.f, 0.f, 0.f, 0.f},
                  {0.f, 0.f, 0.f, 0.f}};
  float scal[3] = {1.f, amp, att};
  const bf16x8* Bp = (const bf16x8*)Bf;
#pragma unroll
  for (int kt = 0; kt < 12; kt++) {
    const float* ag = (kt < 3) ? sv : (kt < 6) ? xv : (kt < 9) ? nv : qv;
    float sc = scal[kt % 3];
    bf16x8 af;
#pragma unroll
    for (int i = 0; i < 8; i++) af[i] = f2bf(ag[i] * sc);
#pragma unroll
    for (int ct = 0; ct < 4; ct++) {
      acc[ct] = __builtin_amdgcn_mfma_f32_16x16x32_bf16(af, Bp[(kt * 4 + ct) * 64 + lane],
                                                        acc[ct], 0, 0, 0);
    }
  }

#pragma unroll
  for (int ct = 0; ct < 4; ct++) {
    int ocol = ct * 16 + r;
    float bb = bias[ocol];
#pragma unroll
    for (int j = 0; j < 4; j++) {
      int orow = nb + oct * 4 + j;
      out[orow * 64 + ocol] = acc[ct][j] + bb;
    }
  }
}

extern "C" void kernel_launch(void* const* d_in, const int* in_sizes, int n_in,
                              void* d_out, int out_size, void* d_ws, size_t ws_size,
                              hipStream_t stream) {
  const float* msg = (const float*)d_in[0];
  const int* dst = (const int*)d_in[1];
  const float* W = (const float*)d_in[3];
  const float* bias = (const float*)d_in[4];
  float* out = (float*)d_out;

  int* wsi = (int*)d_ws;
  int2* pairs = (int2*)wsi;                 // 2*NE ints (8B aligned at base)
  int* eid = wsi + 2 * NE;                  // NE
  int* off = wsi + 3 * NE;                  // NN+1
  int* bktcnt = wsi + 3 * NE + NN + 1;      // NBKT
  int* bktoff = bktcnt + NBKT;              // NBKT+1
  int* bkcur = bktoff + NBKT + 1;           // NBKT

  k_init0<<<1, 512, 0, stream>>>(bktcnt);
  k_bktcount<<<NBINBLK, 256, 0, stream>>>(dst, bktcnt);
  k_bktscan<<<1, 512, 0, stream>>>(bktcnt, bktoff, bkcur, off);
  k_bin<<<NBINBLK, 256, 0, stream>>>(dst, bkcur, pairs);
  k_build<<<NBKT, 256, 0, stream>>>(pairs, bktoff, off, eid);
  k_fused<<<(NN / 16 + 7) / 8, 512, 0, stream>>>(msg, off, eid, W, bias, out);
}